// Round 8
// baseline (288.322 us; speedup 1.0000x reference)
//
#include <hip/hip_runtime.h>
#include <hip/hip_bf16.h>

#define DEV static __device__ __forceinline__

typedef __attribute__((ext_vector_type(4))) float f32x4;
typedef __attribute__((ext_vector_type(8))) short bf16x8;
typedef __attribute__((ext_vector_type(8))) _Float16 half8;
typedef __attribute__((ext_vector_type(8))) unsigned short u16x8;

DEV float leakys(float v) { return v > 0.f ? v : 0.2f * v; }
DEV float4 add4(float4 a, float4 b) { return make_float4(a.x+b.x, a.y+b.y, a.z+b.z, a.w+b.w); }
DEV float4 leaky4(float4 v) { return make_float4(leakys(v.x), leakys(v.y), leakys(v.z), leakys(v.w)); }
DEV float4 exp4(float4 v) { return make_float4(__expf(v.x), __expf(v.y), __expf(v.z), __expf(v.w)); }
DEV float pick4(float4 v, int i) {
    float r = v.x;
    r = (i == 1) ? v.y : r;
    r = (i == 2) ? v.z : r;
    r = (i == 3) ? v.w : r;
    return r;
}

DEV ushort f2bf(float f) {
    union { float f; unsigned u; } v; v.f = f;
    unsigned u = v.u;
    unsigned r = (u + 0x7FFFu + ((u >> 16) & 1u)) >> 16;   // RNE
    return (ushort)r;
}
DEV float bf2f(ushort h) {
    union { unsigned u; float f; } v; v.u = ((unsigned)h) << 16;
    return v.f;
}
DEV ushort f2h(float f) {
    union { _Float16 h; ushort u; } v;
    v.h = (_Float16)f;
    return v.u;
}

// ---------------------------------------------------------------------------
// One-time W prep: W[K=128][NC] f32 -> transposed bf16 hi/lo  Wt[n][k].
// ---------------------------------------------------------------------------
__global__ void prep_w(const float* __restrict__ W, ushort* __restrict__ Wth,
                       ushort* __restrict__ Wtl, int NC) {
    int i = blockIdx.x * 256 + threadIdx.x;
    if (i >= 128 * NC) return;
    int k = i / NC, n = i % NC;
    float v = W[i];
    ushort hi = f2bf(v);
    ushort lo = f2bf(v - bf2f(hi));
    Wth[n * 128 + k] = hi;
    Wtl[n * 128 + k] = lo;
}

// ---------------------------------------------------------------------------
// MFMA GEMM: C[N][NCOLS] = A[N][128] @ W[128][NCOLS], split-bf16 (3 MFMA).
// A is f32 (AH=false) or fp16 (AH=true). Output: fp16 C16 only.
// Fused attention dots (see NT==2 / else branches).
// ---------------------------------------------------------------------------
template <int NCOLS, bool AH>
__launch_bounds__(256, 2)
__global__ void gemm_mfma(const float* __restrict__ A, const ushort* __restrict__ A16,
                          const ushort* __restrict__ Wth, const ushort* __restrict__ Wtl,
                          ushort* __restrict__ C16,
                          const float* __restrict__ att_s, const float* __restrict__ att_d,
                          float* __restrict__ as_out, float* __restrict__ ad_out, int N) {
    constexpr int NT = NCOLS / 64;          // 16-wide n-tiles per wave
    __shared__ ushort Xhi[64 * 128];
    __shared__ ushort Xlo[64 * 128];
    __shared__ float pbs[64][4];
    __shared__ float pbd[64][4];
    const int t = threadIdx.x;
    const int wv = t >> 6, l = t & 63;
    const int l15 = l & 15, lhi = l >> 4;
    const int row0 = blockIdx.x * 64;
    const int n0 = wv * 16 * NT;

    if constexpr (!AH) {
        for (int i = t; i < 2048; i += 256) {
            int r = i >> 5, c4 = i & 31;
            int gr = row0 + r;
            float4 v = make_float4(0.f, 0.f, 0.f, 0.f);
            if (gr < N) v = ((const float4*)A)[(size_t)gr * 32 + c4];
            ushort4 hi, lo;
            hi.x = f2bf(v.x); lo.x = f2bf(v.x - bf2f(hi.x));
            hi.y = f2bf(v.y); lo.y = f2bf(v.y - bf2f(hi.y));
            hi.z = f2bf(v.z); lo.z = f2bf(v.z - bf2f(hi.z));
            hi.w = f2bf(v.w); lo.w = f2bf(v.w - bf2f(hi.w));
            int idx = (r * 128 + c4 * 4) ^ ((r & 7) << 3);
            *(ushort4*)&Xhi[idx] = hi;
            *(ushort4*)&Xlo[idx] = lo;
        }
    } else {
        for (int i = t; i < 1024; i += 256) {
            int r = i >> 4, c8 = i & 15;
            int gr = row0 + r;
            half8 v = (half8){0, 0, 0, 0, 0, 0, 0, 0};
            if (gr < N) v = *(const half8*)&A16[(size_t)gr * 128 + c8 * 8];
            u16x8 hi, lo;
#pragma unroll
            for (int j = 0; j < 8; j++) {
                float f = (float)v[j];
                ushort hb = f2bf(f);
                hi[j] = hb;
                lo[j] = f2bf(f - bf2f(hb));
            }
            int idx = (r * 128 + c8 * 8) ^ ((r & 7) << 3);
            *(u16x8*)&Xhi[idx] = hi;
            *(u16x8*)&Xlo[idx] = lo;
        }
    }
    __syncthreads();

    f32x4 acc[4][NT];
#pragma unroll
    for (int mt = 0; mt < 4; mt++)
#pragma unroll
        for (int nt = 0; nt < NT; nt++) acc[mt][nt] = (f32x4){0.f, 0.f, 0.f, 0.f};

#pragma unroll
    for (int ks = 0; ks < 4; ks++) {
        bf16x8 ah[4], al[4];
#pragma unroll
        for (int mt = 0; mt < 4; mt++) {
            int row = mt * 16 + l15;
            int idx = (row * 128 + ks * 32 + lhi * 8) ^ ((row & 7) << 3);
            ah[mt] = *(const bf16x8*)&Xhi[idx];
            al[mt] = *(const bf16x8*)&Xlo[idx];
        }
#pragma unroll
        for (int nt = 0; nt < NT; nt++) {
            size_t wo = (size_t)(n0 + nt * 16 + l15) * 128 + ks * 32 + lhi * 8;
            bf16x8 bh = *(const bf16x8*)&Wth[wo];
            bf16x8 bl = *(const bf16x8*)&Wtl[wo];
#pragma unroll
            for (int mt = 0; mt < 4; mt++) {
                acc[mt][nt] = __builtin_amdgcn_mfma_f32_16x16x32_bf16(ah[mt], bh, acc[mt][nt], 0, 0, 0);
                acc[mt][nt] = __builtin_amdgcn_mfma_f32_16x16x32_bf16(ah[mt], bl, acc[mt][nt], 0, 0, 0);
                acc[mt][nt] = __builtin_amdgcn_mfma_f32_16x16x32_bf16(al[mt], bh, acc[mt][nt], 0, 0, 0);
            }
        }
    }
#pragma unroll
    for (int mt = 0; mt < 4; mt++) {
#pragma unroll
        for (int j = 0; j < 4; j++) {
            int gr = row0 + mt * 16 + lhi * 4 + j;
            if (gr < N) {
#pragma unroll
                for (int nt = 0; nt < NT; nt++)
                    C16[(size_t)gr * NCOLS + n0 + nt * 16 + l15] = f2h(acc[mt][nt][j]);
            }
        }
    }
    if constexpr (NT == 2) {
        // fused attdot, H=4: head wv = cols [n0, n0+32)
        float as0 = att_s[n0 + l15],       ad0 = att_d[n0 + l15];
        float as1v = att_s[n0 + 16 + l15], ad1v = att_d[n0 + 16 + l15];
#pragma unroll
        for (int mt = 0; mt < 4; mt++) {
#pragma unroll
            for (int j = 0; j < 4; j++) {
                float ps = acc[mt][0][j] * as0 + acc[mt][1][j] * as1v;
                float pd = acc[mt][0][j] * ad0 + acc[mt][1][j] * ad1v;
#pragma unroll
                for (int o = 1; o < 16; o <<= 1) {
                    ps += __shfl_xor(ps, o);
                    pd += __shfl_xor(pd, o);
                }
                if (l15 == 0) {
                    int gr = row0 + mt * 16 + lhi * 4 + j;
                    if (gr < N) {
                        as_out[gr * 4 + wv] = ps;
                        ad_out[gr * 4 + wv] = pd;
                    }
                }
            }
        }
    } else {
        // fused attdot, H=1: wave partials over 16 cols -> LDS -> combine
        float as0 = att_s[n0 + l15], ad0 = att_d[n0 + l15];
#pragma unroll
        for (int mt = 0; mt < 4; mt++) {
#pragma unroll
            for (int j = 0; j < 4; j++) {
                float ps = acc[mt][0][j] * as0;
                float pd = acc[mt][0][j] * ad0;
#pragma unroll
                for (int o = 1; o < 16; o <<= 1) {
                    ps += __shfl_xor(ps, o);
                    pd += __shfl_xor(pd, o);
                }
                if (l15 == 0) {
                    int rl = mt * 16 + lhi * 4 + j;
                    pbs[rl][wv] = ps;
                    pbd[rl][wv] = pd;
                }
            }
        }
        __syncthreads();
        if (t < 64) {
            int gr = row0 + t;
            if (gr < N) {
                as_out[gr] = pbs[t][0] + pbs[t][1] + pbs[t][2] + pbs[t][3];
                ad_out[gr] = pbd[t][0] + pbd[t][1] + pbd[t][2] + pbd[t][3];
            }
        }
    }
}

// ---------------------------------------------------------------------------
// CSR build, bucket counting sort (unchanged).
// ---------------------------------------------------------------------------
__global__ void bcount(const int* __restrict__ dstIdx, int* __restrict__ bcounts, int E) {
    __shared__ int hist[256];
    int t = threadIdx.x;
    hist[t] = 0;
    __syncthreads();
    for (int e = blockIdx.x * 256 + t; e < E; e += gridDim.x * 256)
        atomicAdd(&hist[dstIdx[e] >> 9], 1);
    __syncthreads();
    int h = hist[t];
    if (h) atomicAdd(&bcounts[t], h);
}

__global__ void bscan(const int* __restrict__ bcounts, int* __restrict__ bbase,
                      int* __restrict__ bcursor, int NB) {
    __shared__ int lds[256];
    int t = threadIdx.x;
    int v = (t < NB) ? bcounts[t] : 0;
    lds[t] = v;
    __syncthreads();
    int val = v;
    for (int o = 1; o < 256; o <<= 1) {
        int other = (t >= o) ? lds[t - o] : 0;
        __syncthreads();
        val += other; lds[t] = val;
        __syncthreads();
    }
    if (t < NB) { bbase[t] = val - v; bcursor[t] = val - v; }
}

__global__ void bscatter(const int* __restrict__ srcIdx, const int* __restrict__ dstIdx,
                         int* __restrict__ bcursor, uint2* __restrict__ ebuf, int E) {
    __shared__ int hist[256];
    __shared__ int gofs[256];
    int t = threadIdx.x;
    hist[t] = 0;
    __syncthreads();
    int e0 = blockIdx.x * 4096;
    int e1 = min(E, e0 + 4096);
    for (int e = e0 + t; e < e1; e += 256)
        atomicAdd(&hist[dstIdx[e] >> 9], 1);
    __syncthreads();
    int h = hist[t];
    if (h) gofs[t] = atomicAdd(&bcursor[t], h);
    __syncthreads();
    hist[t] = 0;
    __syncthreads();
    for (int e = e0 + t; e < e1; e += 256) {
        int d = dstIdx[e];
        int b = d >> 9;
        int r = atomicAdd(&hist[b], 1);
        uint2 v; v.x = (unsigned)srcIdx[e]; v.y = (unsigned)d;
        ebuf[gofs[b] + r] = v;
    }
}

__global__ void bfill(const uint2* __restrict__ ebuf, const int* __restrict__ bbase,
                      int* __restrict__ rowptr, int* __restrict__ esrc,
                      int N, int NB, int E) {
    __shared__ int cnt[512];
    __shared__ int lds[256];
    int b = blockIdx.x, t = threadIdx.x;
    int n0 = b << 9;
    cnt[t] = 0; cnt[t + 256] = 0;
    __syncthreads();
    int e0 = bbase[b];
    int e1 = (b + 1 < NB) ? bbase[b + 1] : E;
    for (int e = e0 + t; e < e1; e += 256)
        atomicAdd(&cnt[ebuf[e].y & 511], 1);
    __syncthreads();
    int c0 = cnt[2 * t], c1 = cnt[2 * t + 1];
    int s = c0 + c1;
    lds[t] = s;
    __syncthreads();
    int val = s;
    for (int o = 1; o < 256; o <<= 1) {
        int other = (t >= o) ? lds[t - o] : 0;
        __syncthreads();
        val += other; lds[t] = val;
        __syncthreads();
    }
    int p = val - s;           // exclusive prefix of this thread's pair
    int nrem = N - n0;
    if (2 * t < nrem)     rowptr[n0 + 2 * t]     = e0 + p;
    if (2 * t + 1 < nrem) rowptr[n0 + 2 * t + 1] = e0 + p + c0;
    cnt[2 * t] = p; cnt[2 * t + 1] = p + c0;   // local cursors
    __syncthreads();
    for (int e = e0 + t; e < e1; e += 256) {
        uint2 ed = ebuf[e];
        int r = atomicAdd(&cnt[ed.y & 511], 1);
        esrc[e0 + r] = (int)ed.x;
    }
    if (b == 0 && t == 0) rowptr[N] = E;
}

// ---------------------------------------------------------------------------
// Layer-1 aggregation: TWO dst nodes per wave (A,B), fused phases for MLP.
// Phase 1: both nodes' esrc+as1 loads issue together, weights once ->
// per-wave LDS. Phase 2: fused gather loop, A and B rows in same body
// (4 outstanding 256B gathers with unroll 2). m=0 softmax; fp16 rows.
// ---------------------------------------------------------------------------
__launch_bounds__(256)
__global__ void aggregate1(const ushort* __restrict__ h16,
                           const float* __restrict__ as1, const float* __restrict__ ad1,
                           const int* __restrict__ rowptr, const int* __restrict__ esrc,
                           const float* __restrict__ b1, ushort* __restrict__ out1h, int N) {
    __shared__ float wbuf[8][256];
    __shared__ int   sbuf[8][64];
    int wid = threadIdx.x >> 6, lane = threadIdx.x & 63;
    int nodeA = blockIdx.x * 8 + wid * 2;
    if (nodeA >= N) return;
    int nodeB = nodeA + 1;
    bool actB = nodeB < N;
    int nB = actB ? nodeB : nodeA;
    int slotA = wid * 2, slotB = wid * 2 + 1;

    float4 asnA = *(const float4*)&as1[nodeA * 4];
    float4 adnA = *(const float4*)&ad1[nodeA * 4];
    float4 asnB = *(const float4*)&as1[nB * 4];
    float4 adnB = *(const float4*)&ad1[nB * 4];
    float4 selfwA = exp4(leaky4(add4(asnA, adnA)));
    float4 selfwB = exp4(leaky4(add4(asnB, adnB)));
    int startA = rowptr[nodeA], endA = rowptr[nodeA + 1];
    int startB = rowptr[nB];
    int endB = actB ? rowptr[nB + 1] : startB;

    int q = lane >> 4, c = lane & 15, hh = c >> 2;
    float4 ssumA = make_float4(0.f, 0.f, 0.f, 0.f);
    float4 ssumB = make_float4(0.f, 0.f, 0.f, 0.f);
    float accA[8] = {0.f, 0.f, 0.f, 0.f, 0.f, 0.f, 0.f, 0.f};
    float accB[8] = {0.f, 0.f, 0.f, 0.f, 0.f, 0.f, 0.f, 0.f};

    int baseA = startA, baseB = startB;
    while (baseA < endA || baseB < endB) {
        int cntA = endA - baseA; if (cntA > 64) cntA = 64; if (cntA < 0) cntA = 0;
        int cntB = endB - baseB; if (cntB > 64) cntB = 64; if (cntB < 0) cntB = 0;
        // phase 1: both nodes' loads issue before the exps
        int eA = baseA + lane; bool vA = eA < endA;
        int eB = baseB + lane; bool vB = eB < endB;
        int sA = vA ? esrc[eA] : 0;
        int sB = vB ? esrc[eB] : 0;
        float4 aA = *(const float4*)&as1[sA * 4];
        float4 aB = *(const float4*)&as1[sB * 4];
        float4 wA = exp4(leaky4(add4(aA, adnA)));
        float4 wB = exp4(leaky4(add4(aB, adnB)));
        if (!vA) wA = make_float4(0.f, 0.f, 0.f, 0.f);
        if (!vB) wB = make_float4(0.f, 0.f, 0.f, 0.f);
        sbuf[slotA][lane] = sA; *(float4*)&wbuf[slotA][lane * 4] = wA;
        sbuf[slotB][lane] = sB; *(float4*)&wbuf[slotB][lane * 4] = wB;
        ssumA = add4(ssumA, wA);
        ssumB = add4(ssumB, wB);
        // phase 2: fused A/B gather-FMA, 4 edges per node per wave-iter
        int cntM = cntA > cntB ? cntA : cntB;
#pragma unroll 2
        for (int i = 0; i < cntM; i += 4) {
            int ii = i + q;
            int sa = 0; float wa = 0.f;
            if (ii < cntA) { sa = sbuf[slotA][ii]; wa = wbuf[slotA][ii * 4 + hh]; }
            int sb = 0; float wb = 0.f;
            if (ii < cntB) { sb = sbuf[slotB][ii]; wb = wbuf[slotB][ii * 4 + hh]; }
            half8 ha = *(const half8*)&h16[(size_t)sa * 128 + c * 8];
            half8 hb = *(const half8*)&h16[(size_t)sb * 128 + c * 8];
#pragma unroll
            for (int j = 0; j < 8; j++) {
                accA[j] += wa * (float)ha[j];
                accB[j] += wb * (float)hb[j];
            }
        }
        baseA += cntA; baseB += cntB;
    }
#pragma unroll
    for (int o = 1; o < 64; o <<= 1) {
        ssumA.x += __shfl_xor(ssumA.x, o); ssumA.y += __shfl_xor(ssumA.y, o);
        ssumA.z += __shfl_xor(ssumA.z, o); ssumA.w += __shfl_xor(ssumA.w, o);
        ssumB.x += __shfl_xor(ssumB.x, o); ssumB.y += __shfl_xor(ssumB.y, o);
        ssumB.z += __shfl_xor(ssumB.z, o); ssumB.w += __shfl_xor(ssumB.w, o);
    }
    float4 denomA = add4(ssumA, selfwA);
    float4 denomB = add4(ssumB, selfwB);
    float invA = 1.f / (pick4(denomA, hh) + 1e-16f);
    float invB = 1.f / (pick4(denomB, hh) + 1e-16f);
    float swA = pick4(selfwA, hh);
    float swB = pick4(selfwB, hh);

#pragma unroll
    for (int j = 0; j < 8; j++) {
        accA[j] += __shfl_xor(accA[j], 16); accA[j] += __shfl_xor(accA[j], 32);
        accB[j] += __shfl_xor(accB[j], 16); accB[j] += __shfl_xor(accB[j], 32);
    }
    if (q == 0) {
        const float* bb = &b1[c * 8];
        half8 hsA = *(const half8*)&h16[(size_t)nodeA * 128 + c * 8];
        half8 ovA;
#pragma unroll
        for (int j = 0; j < 8; j++) {
            float oj = fmaxf((accA[j] + swA * (float)hsA[j]) * invA + bb[j], 0.f);
            ovA[j] = (_Float16)oj;
        }
        *(half8*)&out1h[(size_t)nodeA * 128 + c * 8] = ovA;
        if (actB) {
            half8 hsB = *(const half8*)&h16[(size_t)nodeB * 128 + c * 8];
            half8 ovB;
#pragma unroll
            for (int j = 0; j < 8; j++) {
                float oj = fmaxf((accB[j] + swB * (float)hsB[j]) * invB + bb[j], 0.f);
                ovB[j] = (_Float16)oj;
            }
            *(half8*)&out1h[(size_t)nodeB * 128 + c * 8] = ovB;
        }
    }
}

// ---------------------------------------------------------------------------
// Layer-2 aggregation (H=1, C=64): two nodes per wave, fused gather loop,
// 8 lanes x 16B = one 128B row, 8 edges per node per wave-iter.
// ---------------------------------------------------------------------------
__launch_bounds__(256)
__global__ void aggregate2(const ushort* __restrict__ h16,
                           const float* __restrict__ as2, const float* __restrict__ ad2,
                           const int* __restrict__ rowptr, const int* __restrict__ esrc,
                           const float* __restrict__ b2, float* __restrict__ out, int N) {
    __shared__ float wbuf[8][64];
    __shared__ int   sbuf[8][64];
    int wid = threadIdx.x >> 6, lane = threadIdx.x & 63;
    int nodeA = blockIdx.x * 8 + wid * 2;
    if (nodeA >= N) return;
    int nodeB = nodeA + 1;
    bool actB = nodeB < N;
    int nB = actB ? nodeB : nodeA;
    int slotA = wid * 2, slotB = wid * 2 + 1;

    float adnA = ad2[nodeA], adnB = ad2[nB];
    float selfwA = __expf(leakys(as2[nodeA] + adnA));
    float selfwB = __expf(leakys(as2[nB] + adnB));
    int startA = rowptr[nodeA], endA = rowptr[nodeA + 1];
    int startB = rowptr[nB];
    int endB = actB ? rowptr[nB + 1] : startB;

    int q = lane >> 3, c = lane & 7;
    float ssumA = 0.f, ssumB = 0.f;
    float accA[8] = {0.f, 0.f, 0.f, 0.f, 0.f, 0.f, 0.f, 0.f};
    float accB[8] = {0.f, 0.f, 0.f, 0.f, 0.f, 0.f, 0.f, 0.f};

    int baseA = startA, baseB = startB;
    while (baseA < endA || baseB < endB) {
        int cntA = endA - baseA; if (cntA > 64) cntA = 64; if (cntA < 0) cntA = 0;
        int cntB = endB - baseB; if (cntB > 64) cntB = 64; if (cntB < 0) cntB = 0;
        int eA = baseA + lane; bool vA = eA < endA;
        int eB = baseB + lane; bool vB = eB < endB;
        int sA = vA ? esrc[eA] : 0;
        int sB = vB ? esrc[eB] : 0;
        float aA = as2[sA], aB = as2[sB];
        float wA = vA ? __expf(leakys(aA + adnA)) : 0.f;
        float wB = vB ? __expf(leakys(aB + adnB)) : 0.f;
        sbuf[slotA][lane] = sA; wbuf[slotA][lane] = wA;
        sbuf[slotB][lane] = sB; wbuf[slotB][lane] = wB;
        ssumA += wA; ssumB += wB;
        int cntM = cntA > cntB ? cntA : cntB;
#pragma unroll 2
        for (int i = 0; i < cntM; i += 8) {
            int ii = i + q;
            int sa = 0; float wa = 0.f;
            if (ii < cntA) { sa = sbuf[slotA][ii]; wa = wbuf[slotA][ii]; }
            int sb = 0; float wb = 0.f;
            if (ii < cntB) { sb = sbuf[slotB][ii]; wb = wbuf[slotB][ii]; }
            half8 ha = *(const half8*)&h16[(size_t)sa * 64 + c * 8];
            half8 hb = *(const half8*)&h16[(size_t)sb * 64 + c * 8];
#pragma unroll
            for (int j = 0; j < 8; j++) {
                accA[j] += wa * (float)ha[j];
                accB[j] += wb * (float)hb[j];
            }
        }
        baseA += cntA; baseB += cntB;
    }
#pragma unroll
    for (int o = 1; o < 64; o <<= 1) { ssumA += __shfl_xor(ssumA, o); ssumB += __shfl_xor(ssumB, o); }
    float invA = 1.f / (ssumA + selfwA + 1e-16f);
    float invB = 1.f / (ssumB + selfwB + 1e-16f);

#pragma unroll
    for (int j = 0; j < 8; j++) {
        accA[j] += __shfl_xor(accA[j], 8);  accA[j] += __shfl_xor(accA[j], 16); accA[j] += __shfl_xor(accA[j], 32);
        accB[j] += __shfl_xor(accB[j], 8);  accB[j] += __shfl_xor(accB[j], 16); accB[j] += __shfl_xor(accB[j], 32);
    }
    if (lane < 8) {
        const float* bb = &b2[c * 8];
        half8 hsA = *(const half8*)&h16[(size_t)nodeA * 64 + c * 8];
        float oA[8];
#pragma unroll
        for (int j = 0; j < 8; j++)
            oA[j] = (accA[j] + selfwA * (float)hsA[j]) * invA + bb[j];
        float4* opA = (float4*)&out[(size_t)nodeA * 64 + c * 8];
        opA[0] = make_float4(oA[0], oA[1], oA[2], oA[3]);
        opA[1] = make_float4(oA[4], oA[5], oA[6], oA[7]);
        if (actB) {
            half8 hsB = *(const half8*)&h16[(size_t)nodeB * 64 + c * 8];
            float oB[8];
#pragma unroll
            for (int j = 0; j < 8; j++)
                oB[j] = (accB[j] + selfwB * (float)hsB[j]) * invB + bb[j];
            float4* opB = (float4*)&out[(size_t)nodeB * 64 + c * 8];
            opB[0] = make_float4(oB[0], oB[1], oB[2], oB[3]);
            opB[1] = make_float4(oB[4], oB[5], oB[6], oB[7]);
        }
    }
}

// ---------------------------------------------------------------------------
extern "C" void kernel_launch(void* const* d_in, const int* in_sizes, int n_in,
                              void* d_out, int out_size, void* d_ws, size_t ws_size,
                              hipStream_t stream) {
    const float* x      = (const float*)d_in[0];
    const int*   ei     = (const int*)d_in[1];
    const float* W1     = (const float*)d_in[2];
    const float* att_s1 = (const float*)d_in[3];
    const float* att_d1 = (const float*)d_in[4];
    const float* b1     = (const float*)d_in[5];
    const float* W2     = (const float*)d_in[6];
    const float* att_s2 = (const float*)d_in[7];
    const float* att_d2 = (const float*)d_in[8];
    const float* b2     = (const float*)d_in[9];

    const int N = in_sizes[0] / 128;
    const int E = in_sizes[1] / 2;
    const int NB = (N + 511) >> 9;         // buckets of 512 dst nodes (<=256)

    char* ws = (char*)d_ws;
    size_t off = 0;
    auto alloc = [&](size_t bytes) -> void* {
        off = (off + 255) & ~(size_t)255;
        void* p = ws + off;
        off += bytes;
        return p;
    };
    ushort* h16   = (ushort*)alloc((size_t)N * 128 * 2);   // layer-1 rows (fp16)
    ushort* out1h = (ushort*)alloc((size_t)N * 128 * 2);   // layer-1 output (fp16)
    float* as1    = (float*)alloc((size_t)N * 4 * 4);
    float* ad1    = (float*)alloc((size_t)N * 4 * 4);
    float* as2    = (float*)alloc((size_t)N * 4);
    float* ad2    = (float*)alloc((size_t)N * 4);
    int*   rowptr = (int*)alloc((size_t)(N + 1) * 4);
    int*   esrc   = (int*)alloc((size_t)E * 4);
    int*   bcounts = (int*)alloc(256 * 4);
    int*   bbase   = (int*)alloc(256 * 4);
    int*   bcursor = (int*)alloc(256 * 4);
    ushort* Wt1h  = (ushort*)alloc(128 * 128 * 2);
    ushort* Wt1l  = (ushort*)alloc(128 * 128 * 2);
    ushort* Wt2h  = (ushort*)alloc(64 * 128 * 2);
    ushort* Wt2l  = (ushort*)alloc(64 * 128 * 2);
    ushort* h16b = h16;           // layer-2 rows reuse h16 (dead after aggregate1)
    uint2* ebuf = (uint2*)out1h;  // E*8 <= N*256 B; consumed before out1h written

    const int* srcIdx = ei;
    const int* dstIdx = ei + E;

    hipMemsetAsync(bcounts, 0, 256 * 4, stream);

    prep_w<<<64, 256, 0, stream>>>(W1, Wt1h, Wt1l, 128);
    prep_w<<<32, 256, 0, stream>>>(W2, Wt2h, Wt2l, 64);

    gemm_mfma<128, false><<<(N + 63) / 64, 256, 0, stream>>>(
        x, nullptr, Wt1h, Wt1l, h16, att_s1, att_d1, as1, ad1, N);

    bcount<<<1024, 256, 0, stream>>>(dstIdx, bcounts, E);
    bscan<<<1, 256, 0, stream>>>(bcounts, bbase, bcursor, NB);
    bscatter<<<(E + 4095) / 4096, 256, 0, stream>>>(srcIdx, dstIdx, bcursor, ebuf, E);
    bfill<<<NB, 256, 0, stream>>>(ebuf, bbase, rowptr, esrc, N, NB, E);

    aggregate1<<<(N + 7) / 8, 256, 0, stream>>>(h16, as1, ad1, rowptr, esrc,
                                                b1, out1h, N);

    gemm_mfma<64, true><<<(N + 63) / 64, 256, 0, stream>>>(
        nullptr, out1h, Wt2h, Wt2l, h16b, att_s2, att_d2, as2, ad2, N);

    aggregate2<<<(N + 7) / 8, 256, 0, stream>>>(h16b, as2, ad2, rowptr, esrc,
                                                b2, (float*)d_out, N);
}

// Round 9
// 278.382 us; speedup vs baseline: 1.0357x; 1.0357x over previous
//
#include <hip/hip_runtime.h>
#include <hip/hip_bf16.h>

#define DEV static __device__ __forceinline__

typedef __attribute__((ext_vector_type(4))) float f32x4;
typedef __attribute__((ext_vector_type(8))) short bf16x8;
typedef __attribute__((ext_vector_type(8))) _Float16 half8;
typedef __attribute__((ext_vector_type(8))) unsigned short u16x8;

DEV float leakys(float v) { return v > 0.f ? v : 0.2f * v; }
DEV float4 add4(float4 a, float4 b) { return make_float4(a.x+b.x, a.y+b.y, a.z+b.z, a.w+b.w); }
DEV float4 leaky4(float4 v) { return make_float4(leakys(v.x), leakys(v.y), leakys(v.z), leakys(v.w)); }
DEV float4 exp4(float4 v) { return make_float4(__expf(v.x), __expf(v.y), __expf(v.z), __expf(v.w)); }
DEV float pick4(float4 v, int i) {
    float r = v.x;
    r = (i == 1) ? v.y : r;
    r = (i == 2) ? v.z : r;
    r = (i == 3) ? v.w : r;
    return r;
}

DEV ushort f2bf(float f) {
    union { float f; unsigned u; } v; v.f = f;
    unsigned u = v.u;
    unsigned r = (u + 0x7FFFu + ((u >> 16) & 1u)) >> 16;   // RNE
    return (ushort)r;
}
DEV float bf2f(ushort h) {
    union { unsigned u; float f; } v; v.u = ((unsigned)h) << 16;
    return v.f;
}
DEV ushort f2h(float f) {
    union { _Float16 h; ushort u; } v;
    v.h = (_Float16)f;
    return v.u;
}

// ---------------------------------------------------------------------------
// One-time W prep: W[K=128][NC] f32 -> transposed bf16 hi/lo  Wt[n][k].
// ---------------------------------------------------------------------------
__global__ void prep_w(const float* __restrict__ W, ushort* __restrict__ Wth,
                       ushort* __restrict__ Wtl, int NC) {
    int i = blockIdx.x * 256 + threadIdx.x;
    if (i >= 128 * NC) return;
    int k = i / NC, n = i % NC;
    float v = W[i];
    ushort hi = f2bf(v);
    ushort lo = f2bf(v - bf2f(hi));
    Wth[n * 128 + k] = hi;
    Wtl[n * 128 + k] = lo;
}

// ---------------------------------------------------------------------------
// MFMA GEMM: C[N][NCOLS] = A[N][128] @ W[128][NCOLS], split-bf16 (3 MFMA).
// A is f32 (AH=false) or fp16 (AH=true). Output: fp16 C16 only.
// Fused attention dots (see NT==2 / else branches).
// ---------------------------------------------------------------------------
template <int NCOLS, bool AH>
__launch_bounds__(256, 2)
__global__ void gemm_mfma(const float* __restrict__ A, const ushort* __restrict__ A16,
                          const ushort* __restrict__ Wth, const ushort* __restrict__ Wtl,
                          ushort* __restrict__ C16,
                          const float* __restrict__ att_s, const float* __restrict__ att_d,
                          float* __restrict__ as_out, float* __restrict__ ad_out, int N) {
    constexpr int NT = NCOLS / 64;          // 16-wide n-tiles per wave
    __shared__ ushort Xhi[64 * 128];
    __shared__ ushort Xlo[64 * 128];
    __shared__ float pbs[64][4];
    __shared__ float pbd[64][4];
    const int t = threadIdx.x;
    const int wv = t >> 6, l = t & 63;
    const int l15 = l & 15, lhi = l >> 4;
    const int row0 = blockIdx.x * 64;
    const int n0 = wv * 16 * NT;

    if constexpr (!AH) {
        for (int i = t; i < 2048; i += 256) {
            int r = i >> 5, c4 = i & 31;
            int gr = row0 + r;
            float4 v = make_float4(0.f, 0.f, 0.f, 0.f);
            if (gr < N) v = ((const float4*)A)[(size_t)gr * 32 + c4];
            ushort4 hi, lo;
            hi.x = f2bf(v.x); lo.x = f2bf(v.x - bf2f(hi.x));
            hi.y = f2bf(v.y); lo.y = f2bf(v.y - bf2f(hi.y));
            hi.z = f2bf(v.z); lo.z = f2bf(v.z - bf2f(hi.z));
            hi.w = f2bf(v.w); lo.w = f2bf(v.w - bf2f(hi.w));
            int idx = (r * 128 + c4 * 4) ^ ((r & 7) << 3);
            *(ushort4*)&Xhi[idx] = hi;
            *(ushort4*)&Xlo[idx] = lo;
        }
    } else {
        for (int i = t; i < 1024; i += 256) {
            int r = i >> 4, c8 = i & 15;
            int gr = row0 + r;
            half8 v = (half8){0, 0, 0, 0, 0, 0, 0, 0};
            if (gr < N) v = *(const half8*)&A16[(size_t)gr * 128 + c8 * 8];
            u16x8 hi, lo;
#pragma unroll
            for (int j = 0; j < 8; j++) {
                float f = (float)v[j];
                ushort hb = f2bf(f);
                hi[j] = hb;
                lo[j] = f2bf(f - bf2f(hb));
            }
            int idx = (r * 128 + c8 * 8) ^ ((r & 7) << 3);
            *(u16x8*)&Xhi[idx] = hi;
            *(u16x8*)&Xlo[idx] = lo;
        }
    }
    __syncthreads();

    f32x4 acc[4][NT];
#pragma unroll
    for (int mt = 0; mt < 4; mt++)
#pragma unroll
        for (int nt = 0; nt < NT; nt++) acc[mt][nt] = (f32x4){0.f, 0.f, 0.f, 0.f};

#pragma unroll
    for (int ks = 0; ks < 4; ks++) {
        bf16x8 ah[4], al[4];
#pragma unroll
        for (int mt = 0; mt < 4; mt++) {
            int row = mt * 16 + l15;
            int idx = (row * 128 + ks * 32 + lhi * 8) ^ ((row & 7) << 3);
            ah[mt] = *(const bf16x8*)&Xhi[idx];
            al[mt] = *(const bf16x8*)&Xlo[idx];
        }
#pragma unroll
        for (int nt = 0; nt < NT; nt++) {
            size_t wo = (size_t)(n0 + nt * 16 + l15) * 128 + ks * 32 + lhi * 8;
            bf16x8 bh = *(const bf16x8*)&Wth[wo];
            bf16x8 bl = *(const bf16x8*)&Wtl[wo];
#pragma unroll
            for (int mt = 0; mt < 4; mt++) {
                acc[mt][nt] = __builtin_amdgcn_mfma_f32_16x16x32_bf16(ah[mt], bh, acc[mt][nt], 0, 0, 0);
                acc[mt][nt] = __builtin_amdgcn_mfma_f32_16x16x32_bf16(ah[mt], bl, acc[mt][nt], 0, 0, 0);
                acc[mt][nt] = __builtin_amdgcn_mfma_f32_16x16x32_bf16(al[mt], bh, acc[mt][nt], 0, 0, 0);
            }
        }
    }
#pragma unroll
    for (int mt = 0; mt < 4; mt++) {
#pragma unroll
        for (int j = 0; j < 4; j++) {
            int gr = row0 + mt * 16 + lhi * 4 + j;
            if (gr < N) {
#pragma unroll
                for (int nt = 0; nt < NT; nt++)
                    C16[(size_t)gr * NCOLS + n0 + nt * 16 + l15] = f2h(acc[mt][nt][j]);
            }
        }
    }
    if constexpr (NT == 2) {
        // fused attdot, H=4: head wv = cols [n0, n0+32)
        float as0 = att_s[n0 + l15],       ad0 = att_d[n0 + l15];
        float as1v = att_s[n0 + 16 + l15], ad1v = att_d[n0 + 16 + l15];
#pragma unroll
        for (int mt = 0; mt < 4; mt++) {
#pragma unroll
            for (int j = 0; j < 4; j++) {
                float ps = acc[mt][0][j] * as0 + acc[mt][1][j] * as1v;
                float pd = acc[mt][0][j] * ad0 + acc[mt][1][j] * ad1v;
#pragma unroll
                for (int o = 1; o < 16; o <<= 1) {
                    ps += __shfl_xor(ps, o);
                    pd += __shfl_xor(pd, o);
                }
                if (l15 == 0) {
                    int gr = row0 + mt * 16 + lhi * 4 + j;
                    if (gr < N) {
                        as_out[gr * 4 + wv] = ps;
                        ad_out[gr * 4 + wv] = pd;
                    }
                }
            }
        }
    } else {
        // fused attdot, H=1: wave partials over 16 cols -> LDS -> combine
        float as0 = att_s[n0 + l15], ad0 = att_d[n0 + l15];
#pragma unroll
        for (int mt = 0; mt < 4; mt++) {
#pragma unroll
            for (int j = 0; j < 4; j++) {
                float ps = acc[mt][0][j] * as0;
                float pd = acc[mt][0][j] * ad0;
#pragma unroll
                for (int o = 1; o < 16; o <<= 1) {
                    ps += __shfl_xor(ps, o);
                    pd += __shfl_xor(pd, o);
                }
                if (l15 == 0) {
                    int rl = mt * 16 + lhi * 4 + j;
                    pbs[rl][wv] = ps;
                    pbd[rl][wv] = pd;
                }
            }
        }
        __syncthreads();
        if (t < 64) {
            int gr = row0 + t;
            if (gr < N) {
                as_out[gr] = pbs[t][0] + pbs[t][1] + pbs[t][2] + pbs[t][3];
                ad_out[gr] = pbd[t][0] + pbd[t][1] + pbd[t][2] + pbd[t][3];
            }
        }
    }
}

// ---------------------------------------------------------------------------
// CSR build, bucket counting sort (unchanged).
// ---------------------------------------------------------------------------
__global__ void bcount(const int* __restrict__ dstIdx, int* __restrict__ bcounts, int E) {
    __shared__ int hist[256];
    int t = threadIdx.x;
    hist[t] = 0;
    __syncthreads();
    for (int e = blockIdx.x * 256 + t; e < E; e += gridDim.x * 256)
        atomicAdd(&hist[dstIdx[e] >> 9], 1);
    __syncthreads();
    int h = hist[t];
    if (h) atomicAdd(&bcounts[t], h);
}

__global__ void bscan(const int* __restrict__ bcounts, int* __restrict__ bbase,
                      int* __restrict__ bcursor, int NB) {
    __shared__ int lds[256];
    int t = threadIdx.x;
    int v = (t < NB) ? bcounts[t] : 0;
    lds[t] = v;
    __syncthreads();
    int val = v;
    for (int o = 1; o < 256; o <<= 1) {
        int other = (t >= o) ? lds[t - o] : 0;
        __syncthreads();
        val += other; lds[t] = val;
        __syncthreads();
    }
    if (t < NB) { bbase[t] = val - v; bcursor[t] = val - v; }
}

__global__ void bscatter(const int* __restrict__ srcIdx, const int* __restrict__ dstIdx,
                         int* __restrict__ bcursor, uint2* __restrict__ ebuf, int E) {
    __shared__ int hist[256];
    __shared__ int gofs[256];
    int t = threadIdx.x;
    hist[t] = 0;
    __syncthreads();
    int e0 = blockIdx.x * 4096;
    int e1 = min(E, e0 + 4096);
    for (int e = e0 + t; e < e1; e += 256)
        atomicAdd(&hist[dstIdx[e] >> 9], 1);
    __syncthreads();
    int h = hist[t];
    if (h) gofs[t] = atomicAdd(&bcursor[t], h);
    __syncthreads();
    hist[t] = 0;
    __syncthreads();
    for (int e = e0 + t; e < e1; e += 256) {
        int d = dstIdx[e];
        int b = d >> 9;
        int r = atomicAdd(&hist[b], 1);
        uint2 v; v.x = (unsigned)srcIdx[e]; v.y = (unsigned)d;
        ebuf[gofs[b] + r] = v;
    }
}

__global__ void bfill(const uint2* __restrict__ ebuf, const int* __restrict__ bbase,
                      int* __restrict__ rowptr, int* __restrict__ esrc,
                      int N, int NB, int E) {
    __shared__ int cnt[512];
    __shared__ int lds[256];
    int b = blockIdx.x, t = threadIdx.x;
    int n0 = b << 9;
    cnt[t] = 0; cnt[t + 256] = 0;
    __syncthreads();
    int e0 = bbase[b];
    int e1 = (b + 1 < NB) ? bbase[b + 1] : E;
    for (int e = e0 + t; e < e1; e += 256)
        atomicAdd(&cnt[ebuf[e].y & 511], 1);
    __syncthreads();
    int c0 = cnt[2 * t], c1 = cnt[2 * t + 1];
    int s = c0 + c1;
    lds[t] = s;
    __syncthreads();
    int val = s;
    for (int o = 1; o < 256; o <<= 1) {
        int other = (t >= o) ? lds[t - o] : 0;
        __syncthreads();
        val += other; lds[t] = val;
        __syncthreads();
    }
    int p = val - s;           // exclusive prefix of this thread's pair
    int nrem = N - n0;
    if (2 * t < nrem)     rowptr[n0 + 2 * t]     = e0 + p;
    if (2 * t + 1 < nrem) rowptr[n0 + 2 * t + 1] = e0 + p + c0;
    cnt[2 * t] = p; cnt[2 * t + 1] = p + c0;   // local cursors
    __syncthreads();
    for (int e = e0 + t; e < e1; e += 256) {
        uint2 ed = ebuf[e];
        int r = atomicAdd(&cnt[ed.y & 511], 1);
        esrc[e0 + r] = (int)ed.x;
    }
    if (b == 0 && t == 0) rowptr[N] = E;
}

// ---------------------------------------------------------------------------
// Layer-1 aggregation: ONE node per wave (round-7 body), per-wave GRID-STRIDE
// over nodes. 2048 blocks stay resident (8/CU); each wave independently walks
// node += nwaves -> no block-retirement imbalance, no launch tail. Self-row
// h16 load hoisted into phase 1 to issue early. m=0 softmax; fp16 rows.
// ---------------------------------------------------------------------------
__launch_bounds__(256)
__global__ void aggregate1(const ushort* __restrict__ h16,
                           const float* __restrict__ as1, const float* __restrict__ ad1,
                           const int* __restrict__ rowptr, const int* __restrict__ esrc,
                           const float* __restrict__ b1, ushort* __restrict__ out1h,
                           int N, int nwaves) {
    __shared__ float wbuf[4][256];
    __shared__ int   sbuf[4][64];
    int wid = threadIdx.x >> 6, lane = threadIdx.x & 63;
    int q = lane >> 4, c = lane & 15;   // group q handles edge i+q; ch 8c..8c+7
    int hh = c >> 2;                    // head of this lane's 8 channels

    for (int node = blockIdx.x * 4 + wid; node < N; node += nwaves) {
        float4 asn = *(const float4*)&as1[node * 4];
        float4 adn = *(const float4*)&ad1[node * 4];
        // self row: issue early (independent of everything below)
        half8 hs = *(const half8*)&h16[(size_t)node * 128 + c * 8];
        float4 selfw = exp4(leaky4(add4(asn, adn)));
        int start = rowptr[node], end = rowptr[node + 1];

        float4 ssum = make_float4(0.f, 0.f, 0.f, 0.f);
        float acc[8] = {0.f, 0.f, 0.f, 0.f, 0.f, 0.f, 0.f, 0.f};

        for (int base = start; base < end; base += 64) {
            int cnt = end - base; if (cnt > 64) cnt = 64;
            // phase 1: per-edge weights (once), denominator partials in regs
            if (lane < cnt) {
                int s = esrc[base + lane];
                float4 w = exp4(leaky4(add4(*(const float4*)&as1[s * 4], adn)));
                sbuf[wid][lane] = s;
                *(float4*)&wbuf[wid][lane * 4] = w;
                ssum = add4(ssum, w);
            }
            // phase 2: fp16 gather-FMA, 4 edges/iter; w,s broadcast from LDS
#pragma unroll 4
            for (int i = 0; i < cnt; i += 4) {
                int ii = i + q;
                int s = 0; float w = 0.f;
                if (ii < cnt) { s = sbuf[wid][ii]; w = wbuf[wid][ii * 4 + hh]; }
                half8 hv = *(const half8*)&h16[(size_t)s * 128 + c * 8];
#pragma unroll
                for (int j = 0; j < 8; j++) acc[j] += w * (float)hv[j];
            }
        }
#pragma unroll
        for (int o = 1; o < 64; o <<= 1) {
            ssum.x += __shfl_xor(ssum.x, o);
            ssum.y += __shfl_xor(ssum.y, o);
            ssum.z += __shfl_xor(ssum.z, o);
            ssum.w += __shfl_xor(ssum.w, o);
        }
        float4 denom = add4(ssum, selfw);
        float inv = 1.f / (pick4(denom, hh) + 1e-16f);
        float sw = pick4(selfw, hh);

#pragma unroll
        for (int j = 0; j < 8; j++) {
            acc[j] += __shfl_xor(acc[j], 16);
            acc[j] += __shfl_xor(acc[j], 32);
        }
        if (q == 0) {
            const float* bb = &b1[c * 8];
            half8 ov;
#pragma unroll
            for (int j = 0; j < 8; j++) {
                float oj = fmaxf((acc[j] + sw * (float)hs[j]) * inv + bb[j], 0.f);
                ov[j] = (_Float16)oj;
            }
            *(half8*)&out1h[(size_t)node * 128 + c * 8] = ov;
        }
    }
}

// ---------------------------------------------------------------------------
// Layer-2 aggregation (H=1, C=64): one node per wave, grid-stride; 8 lanes x
// 16B = one 128B row, 8 edges/iter.
// ---------------------------------------------------------------------------
__launch_bounds__(256)
__global__ void aggregate2(const ushort* __restrict__ h16,
                           const float* __restrict__ as2, const float* __restrict__ ad2,
                           const int* __restrict__ rowptr, const int* __restrict__ esrc,
                           const float* __restrict__ b2, float* __restrict__ out,
                           int N, int nwaves) {
    __shared__ float wbuf[4][64];
    __shared__ int   sbuf[4][64];
    int wid = threadIdx.x >> 6, lane = threadIdx.x & 63;
    int q = lane >> 3, c = lane & 7;    // group q handles edge i+q; ch 8c..8c+7

    for (int node = blockIdx.x * 4 + wid; node < N; node += nwaves) {
        float adn = ad2[node];
        half8 hs = *(const half8*)&h16[(size_t)node * 64 + c * 8];  // early
        float selfw = __expf(leakys(as2[node] + adn));
        int start = rowptr[node], end = rowptr[node + 1];

        float ssum = 0.f;
        float acc[8] = {0.f, 0.f, 0.f, 0.f, 0.f, 0.f, 0.f, 0.f};

        for (int base = start; base < end; base += 64) {
            int cnt = end - base; if (cnt > 64) cnt = 64;
            if (lane < cnt) {
                int s = esrc[base + lane];
                float w = __expf(leakys(as2[s] + adn));
                sbuf[wid][lane] = s;
                wbuf[wid][lane] = w;
                ssum += w;
            }
#pragma unroll 2
            for (int i = 0; i < cnt; i += 8) {
                int ii = i + q;
                int s = 0; float w = 0.f;
                if (ii < cnt) { s = sbuf[wid][ii]; w = wbuf[wid][ii]; }
                half8 hv = *(const half8*)&h16[(size_t)s * 64 + c * 8];
#pragma unroll
                for (int j = 0; j < 8; j++) acc[j] += w * (float)hv[j];
            }
        }
#pragma unroll
        for (int o = 1; o < 64; o <<= 1) ssum += __shfl_xor(ssum, o);
        float inv = 1.f / (ssum + selfw + 1e-16f);

#pragma unroll
        for (int j = 0; j < 8; j++) {
            acc[j] += __shfl_xor(acc[j], 8);
            acc[j] += __shfl_xor(acc[j], 16);
            acc[j] += __shfl_xor(acc[j], 32);
        }
        if (lane < 8) {
            const float* bb = &b2[c * 8];
            float o[8];
#pragma unroll
            for (int j = 0; j < 8; j++)
                o[j] = (acc[j] + selfw * (float)hs[j]) * inv + bb[j];
            float4* op = (float4*)&out[(size_t)node * 64 + c * 8];
            op[0] = make_float4(o[0], o[1], o[2], o[3]);
            op[1] = make_float4(o[4], o[5], o[6], o[7]);
        }
    }
}

// ---------------------------------------------------------------------------
extern "C" void kernel_launch(void* const* d_in, const int* in_sizes, int n_in,
                              void* d_out, int out_size, void* d_ws, size_t ws_size,
                              hipStream_t stream) {
    const float* x      = (const float*)d_in[0];
    const int*   ei     = (const int*)d_in[1];
    const float* W1     = (const float*)d_in[2];
    const float* att_s1 = (const float*)d_in[3];
    const float* att_d1 = (const float*)d_in[4];
    const float* b1     = (const float*)d_in[5];
    const float* W2     = (const float*)d_in[6];
    const float* att_s2 = (const float*)d_in[7];
    const float* att_d2 = (const float*)d_in[8];
    const float* b2     = (const float*)d_in[9];

    const int N = in_sizes[0] / 128;
    const int E = in_sizes[1] / 2;
    const int NB = (N + 511) >> 9;         // buckets of 512 dst nodes (<=256)

    char* ws = (char*)d_ws;
    size_t off = 0;
    auto alloc = [&](size_t bytes) -> void* {
        off = (off + 255) & ~(size_t)255;
        void* p = ws + off;
        off += bytes;
        return p;
    };
    ushort* h16   = (ushort*)alloc((size_t)N * 128 * 2);   // layer-1 rows (fp16)
    ushort* out1h = (ushort*)alloc((size_t)N * 128 * 2);   // layer-1 output (fp16)
    float* as1    = (float*)alloc((size_t)N * 4 * 4);
    float* ad1    = (float*)alloc((size_t)N * 4 * 4);
    float* as2    = (float*)alloc((size_t)N * 4);
    float* ad2    = (float*)alloc((size_t)N * 4);
    int*   rowptr = (int*)alloc((size_t)(N + 1) * 4);
    int*   esrc   = (int*)alloc((size_t)E * 4);
    int*   bcounts = (int*)alloc(256 * 4);
    int*   bbase   = (int*)alloc(256 * 4);
    int*   bcursor = (int*)alloc(256 * 4);
    ushort* Wt1h  = (ushort*)alloc(128 * 128 * 2);
    ushort* Wt1l  = (ushort*)alloc(128 * 128 * 2);
    ushort* Wt2h  = (ushort*)alloc(64 * 128 * 2);
    ushort* Wt2l  = (ushort*)alloc(64 * 128 * 2);
    ushort* h16b = h16;           // layer-2 rows reuse h16 (dead after aggregate1)
    uint2* ebuf = (uint2*)out1h;  // E*8 <= N*256 B; consumed before out1h written

    const int* srcIdx = ei;
    const int* dstIdx = ei + E;

    const int AGG_BLOCKS = 2048;           // 8 blocks/CU resident
    const int NWAVES = AGG_BLOCKS * 4;

    hipMemsetAsync(bcounts, 0, 256 * 4, stream);

    prep_w<<<64, 256, 0, stream>>>(W1, Wt1h, Wt1l, 128);
    prep_w<<<32, 256, 0, stream>>>(W2, Wt2h, Wt2l, 64);

    gemm_mfma<128, false><<<(N + 63) / 64, 256, 0, stream>>>(
        x, nullptr, Wt1h, Wt1l, h16, att_s1, att_d1, as1, ad1, N);

    bcount<<<1024, 256, 0, stream>>>(dstIdx, bcounts, E);
    bscan<<<1, 256, 0, stream>>>(bcounts, bbase, bcursor, NB);
    bscatter<<<(E + 4095) / 4096, 256, 0, stream>>>(srcIdx, dstIdx, bcursor, ebuf, E);
    bfill<<<NB, 256, 0, stream>>>(ebuf, bbase, rowptr, esrc, N, NB, E);

    aggregate1<<<AGG_BLOCKS, 256, 0, stream>>>(h16, as1, ad1, rowptr, esrc,
                                               b1, out1h, N, NWAVES);

    gemm_mfma<64, true><<<(N + 63) / 64, 256, 0, stream>>>(
        nullptr, out1h, Wt2h, Wt2l, h16b, att_s2, att_d2, as2, ad2, N);

    aggregate2<<<AGG_BLOCKS, 256, 0, stream>>>(h16b, as2, ad2, rowptr, esrc,
                                               b2, (float*)d_out, N, NWAVES);
}